// Round 2
// baseline (159.953 us; speedup 1.0000x reference)
//
#include <hip/hip_runtime.h>

typedef _Float16 half8_t __attribute__((ext_vector_type(8)));
typedef _Float16 half4_t __attribute__((ext_vector_type(4)));
typedef float    float4_t __attribute__((ext_vector_type(4)));

#define N_TILES 1024
#define PTS     256
#define IN_F    256
#define OUT_F   256
#define BM      128         // rows per block (half a tile)
#define BK      32
#define LDK     40          // BK + 8 fp16 pad -> 80 B rows, 16B-aligned b128 frags
#define NSTEP   (IN_F / BK) // 8
#define OMEGA_C 30.0f

// Grid 2048: one block = 128x256 half-tile. 512 threads = 8 waves (2M x 4N),
// per-wave 64x64 output = acc[4][4] (64 VGPR) so 2 blocks/CU fit in regs+LDS.
__global__ __launch_bounds__(512, 4)
void siren_tile_gemm(const float* __restrict__ x,
                     const float* __restrict__ w,
                     const float* __restrict__ bias,
                     const void* __restrict__ idx_raw,
                     float* __restrict__ out) {
  __shared__ __align__(16) _Float16 Al[2][BM][LDK];     // 20,480 B
  __shared__ __align__(16) _Float16 Bl[2][OUT_F][LDK];  // 40,960 B  (total 60 KiB -> 2 blocks/CU)

  const int tid = threadIdx.x;

  // XCD-aware swizzle: both halves of a tile adjacent on the same XCD (wgid%8).
  const int s_id = blockIdx.x;
  const int xcd  = s_id & 7;
  const int k_id = s_id >> 3;            // 0..255
  const int tile = xcd + 8 * (k_id >> 1);
  const int mh   = k_id & 1;             // which 128-row half

  // indices dtype self-detect (int64 per reference; int32 if demoted) — no LDS.
  const int hiw  = ((const int*)idx_raw)[2 * (tid & 63) + 1];
  const bool is32 = __any(hiw != 0);
  const int ch = is32 ? ((const int*)idx_raw)[tile]
                      : (int)(((const long long*)idx_raw)[tile]);

  const float* __restrict__ Xg = x + (size_t)tile * (PTS * IN_F) + (size_t)mh * BM * IN_F;
  const float* __restrict__ Wg = w + (size_t)ch * (IN_F * OUT_F);
  float*       __restrict__ Og = out + (size_t)tile * (PTS * OUT_F) + (size_t)mh * BM * OUT_F;

  const int a_row = tid >> 3;  // 0..63
  const int a_lir = tid & 7;   // float4 slot in k
  const int b_kb  = tid >> 6;  // wave id = k-quad 0..7
  const int b_nb  = tid & 63;  // float4 slot in n

  float4_t acc[4][4];
#pragma unroll
  for (int m = 0; m < 4; ++m)
#pragma unroll
    for (int n = 0; n < 4; ++n)
      acc[m][n] = (float4_t){0.f, 0.f, 0.f, 0.f};

  float4_t a_ld[2], b_ld[4];

  // B-write swizzle: 16B k-group g at row n lives at physical group g^((n>>3)&3).
  // (n>>3 varies with lane -> spreads the 4-row-stride write across banks; the
  //  read side stays balanced because kg->kg^x is a bijection per row.)
#define BSWZ(g, n) (((g) ^ (((n) >> 3) & 3)))

  // ---- prologue: stage k-step 0 into buffer 0 ----
#pragma unroll
  for (int p = 0; p < 2; ++p)
    a_ld[p] = *(const float4_t*)(Xg + (size_t)(a_row + 64 * p) * IN_F + a_lir * 4);
#pragma unroll
  for (int j = 0; j < 4; ++j)
    b_ld[j] = *(const float4_t*)(Wg + (size_t)(b_kb * 4 + j) * OUT_F + b_nb * 4);
#pragma unroll
  for (int p = 0; p < 2; ++p) {
    half4_t h = {(_Float16)a_ld[p].x, (_Float16)a_ld[p].y,
                 (_Float16)a_ld[p].z, (_Float16)a_ld[p].w};
    *(half4_t*)&Al[0][a_row + 64 * p][a_lir * 4] = h;
  }
#pragma unroll
  for (int i = 0; i < 4; ++i) {
    const int n = b_nb * 4 + i;
    half4_t h = {(_Float16)b_ld[0][i], (_Float16)b_ld[1][i],
                 (_Float16)b_ld[2][i], (_Float16)b_ld[3][i]};
    *(half4_t*)&Bl[0][n][BSWZ(b_kb >> 1, n) * 8 + (b_kb & 1) * 4] = h;
  }
  __syncthreads();

  const int lane = tid & 63;
  const int wid  = tid >> 6;
  const int wm   = (wid >> 2) * 64;  // wave M origin (0/64)
  const int wn   = (wid & 3) * 64;   // wave N origin
  const int fr   = lane & 15;
  const int kg   = lane >> 4;

#pragma unroll 2
  for (int s = 0; s < NSTEP; ++s) {
    const int cur = s & 1;
    // early A prefetch (T14 issue-early): held in 8 VGPRs through MFMA
    if (s + 1 < NSTEP) {
      const int k0 = (s + 1) * BK;
#pragma unroll
      for (int p = 0; p < 2; ++p)
        a_ld[p] = *(const float4_t*)(Xg + (size_t)(a_row + 64 * p) * IN_F + k0 + a_lir * 4);
    }

    half8_t af[4], bf[4];
#pragma unroll
    for (int m = 0; m < 4; ++m)
      af[m] = *(const half8_t*)&Al[cur][wm + m * 16 + fr][kg * 8];
#pragma unroll
    for (int n = 0; n < 4; ++n) {
      const int r = wn + n * 16 + fr;
      bf[n] = *(const half8_t*)&Bl[cur][r][BSWZ(kg, r) * 8];
    }

#pragma unroll
    for (int m = 0; m < 4; ++m)
#pragma unroll
      for (int n = 0; n < 4; ++n)
        acc[m][n] = __builtin_amdgcn_mfma_f32_16x16x32_f16(af[m], bf[n], acc[m][n], 0, 0, 0);

    // keep b_ld liveness out of the MFMA region (cap VGPRs for 4 waves/SIMD)
    __builtin_amdgcn_sched_barrier(0);

    if (s + 1 < NSTEP) {
      const int k0 = (s + 1) * BK;
      const int nxt = cur ^ 1;
#pragma unroll
      for (int j = 0; j < 4; ++j)
        b_ld[j] = *(const float4_t*)(Wg + (size_t)(k0 + b_kb * 4 + j) * OUT_F + b_nb * 4);
      // A writes first (a_ld arrived long ago -> partial vmcnt wait)
#pragma unroll
      for (int p = 0; p < 2; ++p) {
        half4_t h = {(_Float16)a_ld[p].x, (_Float16)a_ld[p].y,
                     (_Float16)a_ld[p].z, (_Float16)a_ld[p].w};
        *(half4_t*)&Al[nxt][a_row + 64 * p][a_lir * 4] = h;
      }
#pragma unroll
      for (int i = 0; i < 4; ++i) {
        const int n = b_nb * 4 + i;
        half4_t h = {(_Float16)b_ld[0][i], (_Float16)b_ld[1][i],
                     (_Float16)b_ld[2][i], (_Float16)b_ld[3][i]};
        *(half4_t*)&Bl[nxt][n][BSWZ(b_kb >> 1, n) * 8 + (b_kb & 1) * 4] = h;
      }
      __syncthreads();
    }
  }

  // ---- epilogue: bias + sin (C/D layout: col=lane&15, row=(lane>>4)*4+j) ----
  float bv[4];
#pragma unroll
  for (int n = 0; n < 4; ++n) bv[n] = OMEGA_C * bias[wn + n * 16 + fr];

#pragma unroll
  for (int m = 0; m < 4; ++m) {
#pragma unroll
    for (int n = 0; n < 4; ++n) {
#pragma unroll
      for (int j = 0; j < 4; ++j) {
        const int row = wm + m * 16 + kg * 4 + j;
        const int col = wn + n * 16 + fr;
        Og[(size_t)row * OUT_F + col] = __sinf(fmaf(OMEGA_C, acc[m][n][j], bv[n]));
      }
    }
  }
}

extern "C" void kernel_launch(void* const* d_in, const int* in_sizes, int n_in,
                              void* d_out, int out_size, void* d_ws, size_t ws_size,
                              hipStream_t stream) {
  const float* x    = (const float*)d_in[0];
  const float* w    = (const float*)d_in[1];
  const float* bias = (const float*)d_in[2];
  const void*  idx  = d_in[3];
  float*       out  = (float*)d_out;

  siren_tile_gemm<<<N_TILES * 2, 512, 0, stream>>>(x, w, bias, idx, out);
}